// Round 5
// baseline (458.507 us; speedup 1.0000x reference)
//
#include <hip/hip_runtime.h>
#include <hip/hip_bf16.h>

#define EPS_Z 1e-4f

typedef __attribute__((ext_vector_type(8))) short bf16x8;
typedef __attribute__((ext_vector_type(4))) float f32x4;

__device__ __forceinline__ float b2f(short s) {
    union { unsigned u; float f; } cv;
    cv.u = ((unsigned)(unsigned short)s) << 16;
    return cv.f;
}

__device__ __forceinline__ void gld_lds16(const __hip_bfloat16* g, __hip_bfloat16* l) {
    __builtin_amdgcn_global_load_lds(
        (__attribute__((address_space(1))) void*)(g),
        (__attribute__((address_space(3))) void*)(l),
        16, 0, 0);
}

// One dispatch converting x, W_qkv, W_proj (fp32 -> bf16 RNE, 4 elems/thread).
__global__ __launch_bounds__(256)
void cvt_all(const float* __restrict__ x, const float* __restrict__ wq,
             const float* __restrict__ wp,
             __hip_bfloat16* __restrict__ xb, __hip_bfloat16* __restrict__ wqb,
             __hip_bfloat16* __restrict__ wpb)
{
    const int N4X = 25088 * 768 / 4;          // 4,816,896
    const int N4Q = 2304 * 768 / 4;           //   442,368
    const int N4P = 768 * 768 / 4;            //   147,456
    int i = blockIdx.x * 256 + threadIdx.x;
    const float* src;
    __hip_bfloat16* dst;
    int idx;
    if (i < N4X)            { src = x;  dst = xb;  idx = i; }
    else if (i < N4X + N4Q) { src = wq; dst = wqb; idx = i - N4X; }
    else if (i < N4X + N4Q + N4P) { src = wp; dst = wpb; idx = i - N4X - N4Q; }
    else return;
    float4 v = ((const float4*)src)[idx];
    union { short4 s; __hip_bfloat16 h[4]; } o;
    o.h[0] = __float2bfloat16(v.x);
    o.h[1] = __float2bfloat16(v.y);
    o.h[2] = __float2bfloat16(v.z);
    o.h[3] = __float2bfloat16(v.w);
    ((short4*)dst)[idx] = o.s;
}

// C[M,N] = A[M,K] @ B[N,K]^T ; A,B bf16, fp32 accumulate. 128x128 tile.
// PROVEN ~95 us (929 TF) on the QKV shape as a single full-grid dispatch.
// Bijective XCD swizzle (m204); identical to the old mapping when grid%8==0.
// MODE 1: relu on cols < 1536, C bf16.
template<int MODE, typename CT>
__global__ __launch_bounds__(256, 3)
void gemm_bt(const __hip_bfloat16* __restrict__ A,
             const __hip_bfloat16* __restrict__ B,
             CT* __restrict__ C,
             const float* __restrict__ bias,
             int K, int N, int gx)
{
    __shared__ __align__(16) __hip_bfloat16 As[128 * 64];
    __shared__ __align__(16) __hip_bfloat16 Bs[128 * 64];
    const int nwg = (int)gridDim.x;
    const int g = blockIdx.x;
    const int xcd = g & 7, lin = g >> 3;
    const int q = nwg >> 3, r = nwg & 7;
    const int gp = (xcd < r ? xcd * (q + 1) : r * (q + 1) + (xcd - r) * q) + lin;
    const int bx = gp % gx;
    const int by = gp / gx;

    const int tid = threadIdx.x;
    const int w = tid >> 6;
    const int l = tid & 63;
    const int wr = (w >> 1) * 64;
    const int wc = (w & 1) * 64;
    const int l15 = l & 15;
    const int lq = l >> 4;
    const int rx = l15 & 7;

    f32x4 acc[4][4] = {};

    const int srow8 = l >> 3;
    const int scol = (((l & 7) ^ (l >> 3)) << 3);

    const __hip_bfloat16* Ab = A + (size_t)by * 128 * K;
    const __hip_bfloat16* Bb = B + (size_t)bx * 128 * K;

    for (int k0 = 0; k0 < K; k0 += 64) {
        __syncthreads();
        #pragma unroll
        for (int i = 0; i < 4; ++i) {
            const int chunk = w * 4 + i;
            const int row = chunk * 8 + srow8;
            gld_lds16(Ab + (size_t)row * K + (k0 + scol), As + chunk * 512);
            gld_lds16(Bb + (size_t)row * K + (k0 + scol), Bs + chunk * 512);
        }
        __syncthreads();
        #pragma unroll
        for (int kk = 0; kk < 64; kk += 32) {
            const int kb = (kk >> 3) + lq;
            const int col = (kb ^ rx) << 3;
            bf16x8 a[4], b[4];
            #pragma unroll
            for (int i = 0; i < 4; ++i)
                a[i] = *(const bf16x8*)(As + (wr + i * 16 + l15) * 64 + col);
            #pragma unroll
            for (int j = 0; j < 4; ++j)
                b[j] = *(const bf16x8*)(Bs + (wc + j * 16 + l15) * 64 + col);
            #pragma unroll
            for (int i = 0; i < 4; ++i)
                #pragma unroll
                for (int j = 0; j < 4; ++j)
                    acc[i][j] = __builtin_amdgcn_mfma_f32_16x16x32_bf16(a[i], b[j], acc[i][j], 0, 0, 0);
        }
    }

    const int crow0 = by * 128 + wr + lq * 4;
    const int ccol0 = bx * 128 + wc + l15;
    #pragma unroll
    for (int i = 0; i < 4; ++i) {
        #pragma unroll
        for (int j = 0; j < 4; ++j) {
            const int gc = ccol0 + j * 16;
            const float badd = (MODE == 2) ? bias[gc] : 0.0f;
            #pragma unroll
            for (int r2 = 0; r2 < 4; ++r2) {
                const int gr = crow0 + i * 16 + r2;
                float v = acc[i][j][r2];
                if (MODE == 1 && gc < 1536) v = fmaxf(v, 0.0f);
                if (MODE == 2) v += badd;
                if (MODE == 1)
                    ((__hip_bfloat16*)C)[(size_t)gr * N + gc] = __float2bfloat16(v);
                else
                    ((float*)C)[(size_t)gr * N + gc] = v;
            }
        }
    }
}

// kv^T partials: kvp[(bh*7+ck)][d][e] = sum_{s in split ck} v[s,d]*k[s,e]
// ksump[(bh*7+ck)][e] = sum_{s in split ck} k[s,e]  (all-ones A-fragment MFMA)
// Software-pipelined prefetch of next s-block's global loads under MFMA.
__global__ __launch_bounds__(256)
void kv_mfma_kernel(const __hip_bfloat16* __restrict__ qkv,
                    float* __restrict__ kvp, float* __restrict__ ksump)
{
    const int SPLIT = 7;
    const int bh = blockIdx.x / SPLIT;
    const int ck = blockIdx.x % SPLIT;
    const int b = bh / 12, h = bh % 12;

    __shared__ __align__(16) __hip_bfloat16 kT[64 * 40];   // [e][s0..31], stride 40
    __shared__ __align__(16) __hip_bfloat16 vT[64 * 40];   // [d][s0..31]

    const int tid = threadIdx.x;
    const int w = tid >> 6, l = tid & 63;
    const int l15 = l & 15, lq = l >> 4;

    const int half = tid >> 7;        // 0 -> stage k, 1 -> stage v
    const int idx  = tid & 127;
    const int e0 = (idx >> 4) * 8;
    const int sp = idx & 15;

    const size_t rowbase = (size_t)b * 3136 * 2304 + (half ? 1536 : 768) + h * 64 + e0;
    __hip_bfloat16* Tdst = half ? vT : kT;

    f32x4 acc[4] = {};
    f32x4 accks = {};

    bf16x8 ones;
    #pragma unroll
    for (int i = 0; i < 8; ++i) ones[i] = (short)0x3F80;   // bf16 1.0

    const int s_begin = ck * 448;
    const int s_end = s_begin + 448;

    bf16x8 r0 = *(const bf16x8*)(qkv + rowbase + (size_t)(s_begin + 2 * sp) * 2304);
    bf16x8 r1 = *(const bf16x8*)(qkv + rowbase + (size_t)(s_begin + 2 * sp + 1) * 2304);

    for (int s0 = s_begin; s0 < s_end; s0 += 32) {
        __syncthreads();   // previous compute done reading LDS
        #pragma unroll
        for (int qq = 0; qq < 8; ++qq) {
            unsigned pk = ((unsigned)(unsigned short)r0[qq]) |
                          (((unsigned)(unsigned short)r1[qq]) << 16);
            *(unsigned*)(Tdst + (e0 + qq) * 40 + 2 * sp) = pk;
        }
        __syncthreads();   // staged data visible
        if (s0 + 32 < s_end) {   // prefetch next block; hides under MFMA below
            r0 = *(const bf16x8*)(qkv + rowbase + (size_t)(s0 + 32 + 2 * sp) * 2304);
            r1 = *(const bf16x8*)(qkv + rowbase + (size_t)(s0 + 33 + 2 * sp) * 2304);
        }
        bf16x8 a = *(const bf16x8*)(vT + (w * 16 + l15) * 40 + lq * 8);
        bf16x8 bfr[4];
        #pragma unroll
        for (int j = 0; j < 4; ++j)
            bfr[j] = *(const bf16x8*)(kT + (j * 16 + l15) * 40 + lq * 8);
        #pragma unroll
        for (int j = 0; j < 4; ++j)
            acc[j] = __builtin_amdgcn_mfma_f32_16x16x32_bf16(a, bfr[j], acc[j], 0, 0, 0);
        accks = __builtin_amdgcn_mfma_f32_16x16x32_bf16(ones, bfr[w], accks, 0, 0, 0);
    }

    float* kvdst = kvp + ((size_t)(bh * SPLIT + ck) << 12);
    #pragma unroll
    for (int j = 0; j < 4; ++j) {
        const int col = j * 16 + l15;
        #pragma unroll
        for (int r = 0; r < 4; ++r) {
            const int row = w * 16 + lq * 4 + r;
            kvdst[row * 64 + col] = acc[j][r];
        }
    }
    if (lq == 0)
        ksump[(size_t)(bh * SPLIT + ck) * 64 + w * 16 + l15] = accks[0];
}

// Sum the 7 fp32 partials -> kvb (bf16) and ksum (fp32).
__global__ __launch_bounds__(256)
void kv_reduce(const float* __restrict__ kvp, const float* __restrict__ ksump,
               __hip_bfloat16* __restrict__ kvb, float* __restrict__ ksum)
{
    const int SPLIT = 7;
    const int bh = blockIdx.x;
    const int tid = threadIdx.x;

    const float* base = kvp + ((size_t)bh * SPLIT << 12) + tid * 16;
    float4 s0 = {}, s1 = {}, s2 = {}, s3 = {};
    #pragma unroll
    for (int p = 0; p < SPLIT; ++p) {
        const float* bp = base + ((size_t)p << 12);
        float4 a0 = *(const float4*)(bp + 0);
        float4 a1 = *(const float4*)(bp + 4);
        float4 a2 = *(const float4*)(bp + 8);
        float4 a3 = *(const float4*)(bp + 12);
        s0.x += a0.x; s0.y += a0.y; s0.z += a0.z; s0.w += a0.w;
        s1.x += a1.x; s1.y += a1.y; s1.z += a1.z; s1.w += a1.w;
        s2.x += a2.x; s2.y += a2.y; s2.z += a2.z; s2.w += a2.w;
        s3.x += a3.x; s3.y += a3.y; s3.z += a3.z; s3.w += a3.w;
    }
    union { bf16x8 v; __hip_bfloat16 h[8]; } o0, o1;
    o0.h[0] = __float2bfloat16(s0.x); o0.h[1] = __float2bfloat16(s0.y);
    o0.h[2] = __float2bfloat16(s0.z); o0.h[3] = __float2bfloat16(s0.w);
    o0.h[4] = __float2bfloat16(s1.x); o0.h[5] = __float2bfloat16(s1.y);
    o0.h[6] = __float2bfloat16(s1.z); o0.h[7] = __float2bfloat16(s1.w);
    o1.h[0] = __float2bfloat16(s2.x); o1.h[1] = __float2bfloat16(s2.y);
    o1.h[2] = __float2bfloat16(s2.z); o1.h[3] = __float2bfloat16(s2.w);
    o1.h[4] = __float2bfloat16(s3.x); o1.h[5] = __float2bfloat16(s3.y);
    o1.h[6] = __float2bfloat16(s3.z); o1.h[7] = __float2bfloat16(s3.w);
    __hip_bfloat16* dst = kvb + ((size_t)bh << 12) + tid * 16;
    *(bf16x8*)(dst + 0) = o0.v;
    *(bf16x8*)(dst + 8) = o1.v;

    if (tid < 64) {
        float t = 0.0f;
        #pragma unroll
        for (int p = 0; p < SPLIT; ++p)
            t += ksump[(size_t)(bh * SPLIT + p) * 64 + tid];
        ksum[(size_t)bh * 64 + tid] = t;
    }
}

// Fused attention + output projection.
// Block = 256 thr (4 waves), owns 32 contiguous rows of M.
// Phase A: att[32][768] for all 12 heads -> LDS (bf16, identical rounding to the
//   old att HBM path). Waves parallel over (row-tile rt, col-half ch) per head --
//   NOT the serial-head structure that regressed in R4; per-head MFMA work is
//   4-wave parallel.
// Phase B: out[32][768] = att_s @ Wp^T + bias, A-frags from LDS, B-frags (Wp)
//   straight from L2. Two 96-col passes per wave keep VGPR ~120 (3 blocks/CU;
//   LDS 49.7KB also caps at 3).
// Removes: att HBM write (38.5MB) + gemm2 A fetch/staging + one launch.
__global__ __launch_bounds__(256, 3)
void attn_proj(const __hip_bfloat16* __restrict__ qkv,
               const __hip_bfloat16* __restrict__ kvb,
               const float* __restrict__ ksumg,
               const __hip_bfloat16* __restrict__ wpb,
               const float* __restrict__ bias,
               float* __restrict__ out)
{
    __shared__ __align__(16) __hip_bfloat16 att_s[32 * 776];   // stride 776 (bank-spread)

    const int blk = blockIdx.x;             // 784 blocks * 32 rows = 25088
    const size_t m0 = (size_t)blk * 32;
    const int bidx = (int)(m0 / 3136);      // batch index (32 rows never cross b)
    const int tid = threadIdx.x;
    const int w = tid >> 6, l = tid & 63;
    const int l15 = l & 15, lq = l >> 4;
    const int rt = w & 1;                   // row-tile (16 rows)
    const int ch = w >> 1;                  // col-half (32 of 64 head-dims)

    // ---------------- phase A: attention into LDS ----------------
    #pragma unroll 1
    for (int h = 0; h < 12; ++h) {
        const int bh = bidx * 12 + h;
        const __hip_bfloat16* kvh = kvb + ((size_t)bh << 12);
        bf16x8 b0[2], b1[2];
        #pragma unroll
        for (int j = 0; j < 2; ++j) {
            const int col = ch * 32 + j * 16 + l15;
            b0[j] = *(const bf16x8*)(kvh + col * 64 + lq * 8);
            b1[j] = *(const bf16x8*)(kvh + col * 64 + 32 + lq * 8);
        }
        const float* ks = ksumg + (bh << 6);
        float kse[8], kse1[8];
        *(float4*)(kse)      = *(const float4*)(ks + lq * 8);
        *(float4*)(kse + 4)  = *(const float4*)(ks + lq * 8 + 4);
        *(float4*)(kse1)     = *(const float4*)(ks + 32 + lq * 8);
        *(float4*)(kse1 + 4) = *(const float4*)(ks + 32 + lq * 8 + 4);

        const __hip_bfloat16* qrow = qkv + (m0 + rt * 16 + l15) * 2304 + h * 64;
        bf16x8 aq0 = *(const bf16x8*)(qrow + lq * 8);
        bf16x8 aq1 = *(const bf16x8*)(qrow + 32 + lq * 8);

        float zp = 0.0f;
        #pragma unroll
        for (int j = 0; j < 8; ++j)
            zp += b2f(aq0[j]) * kse[j] + b2f(aq1[j]) * kse1[j];
        zp += __shfl_xor(zp, 16);
        zp += __shfl_xor(zp, 32);
        const float zr = 1.0f / (zp + EPS_Z);   // lane i<16 holds z-recip for row i

        f32x4 pacc[2] = {};
        #pragma unroll
        for (int j = 0; j < 2; ++j) {
            pacc[j] = __builtin_amdgcn_mfma_f32_16x16x32_bf16(aq0, b0[j], pacc[j], 0, 0, 0);
            pacc[j] = __builtin_amdgcn_mfma_f32_16x16x32_bf16(aq1, b1[j], pacc[j], 0, 0, 0);
        }

        float zrow[4];
        #pragma unroll
        for (int r = 0; r < 4; ++r) zrow[r] = __shfl(zr, lq * 4 + r);

        #pragma unroll
        for (int j = 0; j < 2; ++j) {
            const int col = h * 64 + ch * 32 + j * 16 + l15;
            #pragma unroll
            for (int r = 0; r < 4; ++r) {
                const int row = rt * 16 + lq * 4 + r;
                att_s[row * 776 + col] = __float2bfloat16(pacc[j][r] * zrow[r]);
            }
        }
    }
    __syncthreads();

    // ---------------- phase B: out = att_s @ Wp^T + bias ----------------
    #pragma unroll 1
    for (int pass = 0; pass < 2; ++pass) {
        const int c0 = w * 192 + pass * 96;   // this wave's 96 output cols
        f32x4 acc[2][6] = {};
        #pragma unroll 1
        for (int k0 = 0; k0 < 768; k0 += 32) {
            bf16x8 a0 = *(const bf16x8*)(att_s + (0 * 16 + l15) * 776 + k0 + lq * 8);
            bf16x8 a1 = *(const bf16x8*)(att_s + (1 * 16 + l15) * 776 + k0 + lq * 8);
            bf16x8 bf[6];
            #pragma unroll
            for (int j = 0; j < 6; ++j)
                bf[j] = *(const bf16x8*)(wpb + (size_t)(c0 + j * 16 + l15) * 768 + k0 + lq * 8);
            #pragma unroll
            for (int j = 0; j < 6; ++j) {
                acc[0][j] = __builtin_amdgcn_mfma_f32_16x16x32_bf16(a0, bf[j], acc[0][j], 0, 0, 0);
                acc[1][j] = __builtin_amdgcn_mfma_f32_16x16x32_bf16(a1, bf[j], acc[1][j], 0, 0, 0);
            }
        }
        #pragma unroll
        for (int j = 0; j < 6; ++j) {
            const int gc = c0 + j * 16 + l15;
            const float badd = bias[gc];
            #pragma unroll
            for (int rt2 = 0; rt2 < 2; ++rt2) {
                #pragma unroll
                for (int r = 0; r < 4; ++r) {
                    const size_t gr = m0 + rt2 * 16 + lq * 4 + r;
                    out[gr * 768 + gc] = acc[rt2][j][r] + badd;
                }
            }
        }
    }
}

extern "C" void kernel_launch(void* const* d_in, const int* in_sizes, int n_in,
                              void* d_out, int out_size, void* d_ws, size_t ws_size,
                              hipStream_t stream)
{
    const float* x      = (const float*)d_in[0];   // [25088, 768]
    const float* W_qkv  = (const float*)d_in[1];   // [2304, 768]
    const float* W_proj = (const float*)d_in[2];   // [768, 768]
    const float* b_proj = (const float*)d_in[3];   // [768]
    float* out = (float*)d_out;

    const int M = 25088, K = 768, N1 = 2304, N2 = 768;
    const int SPLIT = 7;

    __hip_bfloat16* qkv = (__hip_bfloat16*)d_ws;            // M*N1
    __hip_bfloat16* xb  = qkv + (size_t)M * N1;             // M*K
    __hip_bfloat16* wqb = xb + (size_t)M * K;               // N1*K
    __hip_bfloat16* wpb = wqb + (size_t)N1 * K;             // N2*K
    float* kvp   = (float*)(wpb + (size_t)N2 * K);          // 7*96*4096 fp32 partials
    float* ksump = kvp + (size_t)SPLIT * 96 * 4096;         // 7*96*64 fp32 partials
    float* ksum  = ksump + (size_t)SPLIT * 96 * 64;         // 96*64 fp32
    __hip_bfloat16* kvb = (__hip_bfloat16*)(ksum + 96 * 64);// 96*4096 bf16

    const int CVT_TOT = (M * K + N1 * K + N2 * K) / 4;
    cvt_all<<<(CVT_TOT + 255) / 256, 256, 0, stream>>>(x, W_qkv, W_proj, xb, wqb, wpb);

    gemm_bt<1, __hip_bfloat16><<<(M / 128) * (N1 / 128), 256, 0, stream>>>(
        xb, wqb, qkv, nullptr, K, N1, N1 / 128);

    kv_mfma_kernel<<<96 * SPLIT, 256, 0, stream>>>(qkv, kvp, ksump);
    kv_reduce<<<96, 256, 0, stream>>>(kvp, ksump, kvb, ksum);
    attn_proj<<<M / 32, 256, 0, stream>>>(qkv, kvb, ksum, wpb, b_proj, out);
}

// Round 6
// 434.728 us; speedup vs baseline: 1.0547x; 1.0547x over previous
//
#include <hip/hip_runtime.h>
#include <hip/hip_bf16.h>

#define EPS_Z 1e-4f

typedef __attribute__((ext_vector_type(8))) short bf16x8;
typedef __attribute__((ext_vector_type(4))) float f32x4;

__device__ __forceinline__ float b2f(short s) {
    union { unsigned u; float f; } cv;
    cv.u = ((unsigned)(unsigned short)s) << 16;
    return cv.f;
}

__device__ __forceinline__ void gld_lds16(const __hip_bfloat16* g, __hip_bfloat16* l) {
    __builtin_amdgcn_global_load_lds(
        (__attribute__((address_space(1))) void*)(g),
        (__attribute__((address_space(3))) void*)(l),
        16, 0, 0);
}

// One dispatch converting x, W_qkv, W_proj (fp32 -> bf16 RNE, 4 elems/thread).
__global__ __launch_bounds__(256)
void cvt_all(const float* __restrict__ x, const float* __restrict__ wq,
             const float* __restrict__ wp,
             __hip_bfloat16* __restrict__ xb, __hip_bfloat16* __restrict__ wqb,
             __hip_bfloat16* __restrict__ wpb)
{
    const int N4X = 25088 * 768 / 4;          // 4,816,896
    const int N4Q = 2304 * 768 / 4;           //   442,368
    const int N4P = 768 * 768 / 4;            //   147,456
    int i = blockIdx.x * 256 + threadIdx.x;
    const float* src;
    __hip_bfloat16* dst;
    int idx;
    if (i < N4X)            { src = x;  dst = xb;  idx = i; }
    else if (i < N4X + N4Q) { src = wq; dst = wqb; idx = i - N4X; }
    else if (i < N4X + N4Q + N4P) { src = wp; dst = wpb; idx = i - N4X - N4Q; }
    else return;
    float4 v = ((const float4*)src)[idx];
    union { short4 s; __hip_bfloat16 h[4]; } o;
    o.h[0] = __float2bfloat16(v.x);
    o.h[1] = __float2bfloat16(v.y);
    o.h[2] = __float2bfloat16(v.z);
    o.h[3] = __float2bfloat16(v.w);
    ((short4*)dst)[idx] = o.s;
}

// C[M,N] = A[M,K] @ B[N,K]^T ; A,B bf16, fp32 accumulate. 128x128 tile.
// PROVEN ~95 us (929 TF) on the QKV shape. Grid 3528 % 8 == 0 -> swizzle
// identical to the R0-R3 proven mapping. DO NOT TOUCH.
template<int MODE, typename CT>
__global__ __launch_bounds__(256, 3)
void gemm_bt(const __hip_bfloat16* __restrict__ A,
             const __hip_bfloat16* __restrict__ B,
             CT* __restrict__ C,
             const float* __restrict__ bias,
             int K, int N, int gx)
{
    __shared__ __align__(16) __hip_bfloat16 As[128 * 64];
    __shared__ __align__(16) __hip_bfloat16 Bs[128 * 64];
    const int nwg = (int)gridDim.x;
    const int g = blockIdx.x;
    const int xcd = g & 7, lin = g >> 3;
    const int q = nwg >> 3, r = nwg & 7;
    const int gp = (xcd < r ? xcd * (q + 1) : r * (q + 1) + (xcd - r) * q) + lin;
    const int bx = gp % gx;
    const int by = gp / gx;

    const int tid = threadIdx.x;
    const int w = tid >> 6;
    const int l = tid & 63;
    const int wr = (w >> 1) * 64;
    const int wc = (w & 1) * 64;
    const int l15 = l & 15;
    const int lq = l >> 4;
    const int rx = l15 & 7;

    f32x4 acc[4][4] = {};

    const int srow8 = l >> 3;
    const int scol = (((l & 7) ^ (l >> 3)) << 3);

    const __hip_bfloat16* Ab = A + (size_t)by * 128 * K;
    const __hip_bfloat16* Bb = B + (size_t)bx * 128 * K;

    for (int k0 = 0; k0 < K; k0 += 64) {
        __syncthreads();
        #pragma unroll
        for (int i = 0; i < 4; ++i) {
            const int chunk = w * 4 + i;
            const int row = chunk * 8 + srow8;
            gld_lds16(Ab + (size_t)row * K + (k0 + scol), As + chunk * 512);
            gld_lds16(Bb + (size_t)row * K + (k0 + scol), Bs + chunk * 512);
        }
        __syncthreads();
        #pragma unroll
        for (int kk = 0; kk < 64; kk += 32) {
            const int kb = (kk >> 3) + lq;
            const int col = (kb ^ rx) << 3;
            bf16x8 a[4], b[4];
            #pragma unroll
            for (int i = 0; i < 4; ++i)
                a[i] = *(const bf16x8*)(As + (wr + i * 16 + l15) * 64 + col);
            #pragma unroll
            for (int j = 0; j < 4; ++j)
                b[j] = *(const bf16x8*)(Bs + (wc + j * 16 + l15) * 64 + col);
            #pragma unroll
            for (int i = 0; i < 4; ++i)
                #pragma unroll
                for (int j = 0; j < 4; ++j)
                    acc[i][j] = __builtin_amdgcn_mfma_f32_16x16x32_bf16(a[i], b[j], acc[i][j], 0, 0, 0);
        }
    }

    const int crow0 = by * 128 + wr + lq * 4;
    const int ccol0 = bx * 128 + wc + l15;
    #pragma unroll
    for (int i = 0; i < 4; ++i) {
        #pragma unroll
        for (int j = 0; j < 4; ++j) {
            const int gc = ccol0 + j * 16;
            const float badd = (MODE == 2) ? bias[gc] : 0.0f;
            #pragma unroll
            for (int r2 = 0; r2 < 4; ++r2) {
                const int gr = crow0 + i * 16 + r2;
                float v = acc[i][j][r2];
                if (MODE == 1 && gc < 1536) v = fmaxf(v, 0.0f);
                if (MODE == 2) v += badd;
                if (MODE == 1)
                    ((__hip_bfloat16*)C)[(size_t)gr * N + gc] = __float2bfloat16(v);
                else
                    ((float*)C)[(size_t)gr * N + gc] = v;
            }
        }
    }
}

// kv^T partials + ksum partials. Unchanged from R3 (proven).
__global__ __launch_bounds__(256)
void kv_mfma_kernel(const __hip_bfloat16* __restrict__ qkv,
                    float* __restrict__ kvp, float* __restrict__ ksump)
{
    const int SPLIT = 7;
    const int bh = blockIdx.x / SPLIT;
    const int ck = blockIdx.x % SPLIT;
    const int b = bh / 12, h = bh % 12;

    __shared__ __align__(16) __hip_bfloat16 kT[64 * 40];   // [e][s0..31], stride 40
    __shared__ __align__(16) __hip_bfloat16 vT[64 * 40];   // [d][s0..31]

    const int tid = threadIdx.x;
    const int w = tid >> 6, l = tid & 63;
    const int l15 = l & 15, lq = l >> 4;

    const int half = tid >> 7;        // 0 -> stage k, 1 -> stage v
    const int idx  = tid & 127;
    const int e0 = (idx >> 4) * 8;
    const int sp = idx & 15;

    const size_t rowbase = (size_t)b * 3136 * 2304 + (half ? 1536 : 768) + h * 64 + e0;
    __hip_bfloat16* Tdst = half ? vT : kT;

    f32x4 acc[4] = {};
    f32x4 accks = {};

    bf16x8 ones;
    #pragma unroll
    for (int i = 0; i < 8; ++i) ones[i] = (short)0x3F80;   // bf16 1.0

    const int s_begin = ck * 448;
    const int s_end = s_begin + 448;

    bf16x8 r0 = *(const bf16x8*)(qkv + rowbase + (size_t)(s_begin + 2 * sp) * 2304);
    bf16x8 r1 = *(const bf16x8*)(qkv + rowbase + (size_t)(s_begin + 2 * sp + 1) * 2304);

    for (int s0 = s_begin; s0 < s_end; s0 += 32) {
        __syncthreads();   // previous compute done reading LDS
        #pragma unroll
        for (int qq = 0; qq < 8; ++qq) {
            unsigned pk = ((unsigned)(unsigned short)r0[qq]) |
                          (((unsigned)(unsigned short)r1[qq]) << 16);
            *(unsigned*)(Tdst + (e0 + qq) * 40 + 2 * sp) = pk;
        }
        __syncthreads();   // staged data visible
        if (s0 + 32 < s_end) {   // prefetch next block; hides under MFMA below
            r0 = *(const bf16x8*)(qkv + rowbase + (size_t)(s0 + 32 + 2 * sp) * 2304);
            r1 = *(const bf16x8*)(qkv + rowbase + (size_t)(s0 + 33 + 2 * sp) * 2304);
        }
        bf16x8 a = *(const bf16x8*)(vT + (w * 16 + l15) * 40 + lq * 8);
        bf16x8 bfr[4];
        #pragma unroll
        for (int j = 0; j < 4; ++j)
            bfr[j] = *(const bf16x8*)(kT + (j * 16 + l15) * 40 + lq * 8);
        #pragma unroll
        for (int j = 0; j < 4; ++j)
            acc[j] = __builtin_amdgcn_mfma_f32_16x16x32_bf16(a, bfr[j], acc[j], 0, 0, 0);
        accks = __builtin_amdgcn_mfma_f32_16x16x32_bf16(ones, bfr[w], accks, 0, 0, 0);
    }

    float* kvdst = kvp + ((size_t)(bh * SPLIT + ck) << 12);
    #pragma unroll
    for (int j = 0; j < 4; ++j) {
        const int col = j * 16 + l15;
        #pragma unroll
        for (int r = 0; r < 4; ++r) {
            const int row = w * 16 + lq * 4 + r;
            kvdst[row * 64 + col] = acc[j][r];
        }
    }
    if (lq == 0)
        ksump[(size_t)(bh * SPLIT + ck) * 64 + w * 16 + l15] = accks[0];
}

// Sum the 7 fp32 partials -> kvb (bf16) and ksum (fp32). Unchanged from R3.
__global__ __launch_bounds__(256)
void kv_reduce(const float* __restrict__ kvp, const float* __restrict__ ksump,
               __hip_bfloat16* __restrict__ kvb, float* __restrict__ ksum)
{
    const int SPLIT = 7;
    const int bh = blockIdx.x;
    const int tid = threadIdx.x;

    const float* base = kvp + ((size_t)bh * SPLIT << 12) + tid * 16;
    float4 s0 = {}, s1 = {}, s2 = {}, s3 = {};
    #pragma unroll
    for (int p = 0; p < SPLIT; ++p) {
        const float* bp = base + ((size_t)p << 12);
        float4 a0 = *(const float4*)(bp + 0);
        float4 a1 = *(const float4*)(bp + 4);
        float4 a2 = *(const float4*)(bp + 8);
        float4 a3 = *(const float4*)(bp + 12);
        s0.x += a0.x; s0.y += a0.y; s0.z += a0.z; s0.w += a0.w;
        s1.x += a1.x; s1.y += a1.y; s1.z += a1.z; s1.w += a1.w;
        s2.x += a2.x; s2.y += a2.y; s2.z += a2.z; s2.w += a2.w;
        s3.x += a3.x; s3.y += a3.y; s3.z += a3.z; s3.w += a3.w;
    }
    union { bf16x8 v; __hip_bfloat16 h[8]; } o0, o1;
    o0.h[0] = __float2bfloat16(s0.x); o0.h[1] = __float2bfloat16(s0.y);
    o0.h[2] = __float2bfloat16(s0.z); o0.h[3] = __float2bfloat16(s0.w);
    o0.h[4] = __float2bfloat16(s1.x); o0.h[5] = __float2bfloat16(s1.y);
    o0.h[6] = __float2bfloat16(s1.z); o0.h[7] = __float2bfloat16(s1.w);
    o1.h[0] = __float2bfloat16(s2.x); o1.h[1] = __float2bfloat16(s2.y);
    o1.h[2] = __float2bfloat16(s2.z); o1.h[3] = __float2bfloat16(s2.w);
    o1.h[4] = __float2bfloat16(s3.x); o1.h[5] = __float2bfloat16(s3.y);
    o1.h[6] = __float2bfloat16(s3.z); o1.h[7] = __float2bfloat16(s3.w);
    __hip_bfloat16* dst = kvb + ((size_t)bh << 12) + tid * 16;
    *(bf16x8*)(dst + 0) = o0.v;
    *(bf16x8*)(dst + 8) = o1.v;

    if (tid < 64) {
        float t = 0.0f;
        #pragma unroll
        for (int p = 0; p < SPLIT; ++p)
            t += ksump[(size_t)(bh * SPLIT + p) * 64 + tid];
        ksum[(size_t)bh * 64 + tid] = t;
    }
}

// ============================================================================
// Fused attention + output projection, v2 (v1 failure modes fixed):
//  * Phase A: wave w owns heads 3w..3w+2 for all 32 rows (head-PARALLEL across
//    waves), with depth-1 double-buffered prefetch of q (HBM), kv (L2), ksum
//    (L2) -- next head's loads in flight during current head's compute.
//  * Phase B: manual 2-stage (even/odd named regs) pipeline: loads for k+32
//    issued before MFMAs for k. No barriers inside.
//  * att_s stride 772 (not 776): row-delta-4 -> dword-delta 8 (mod 32), lq
//    octets disjoint; reads 2 lanes/bank (free, m136).
// Saves vs separate attn+gemm2: 77 MB att HBM round-trip + one dispatch.
// ============================================================================
#define AS 772

__global__ __launch_bounds__(256, 2)
void attn_proj(const __hip_bfloat16* __restrict__ qkv,
               const __hip_bfloat16* __restrict__ kvb,
               const float* __restrict__ ksumg,
               const __hip_bfloat16* __restrict__ wpb,
               const float* __restrict__ bias,
               float* __restrict__ out)
{
    __shared__ __align__(16) __hip_bfloat16 att_s[32 * AS];   // 49,408 B

    const int blk = blockIdx.x;             // 784 blocks * 32 rows = 25088
    const size_t m0 = (size_t)blk * 32;
    const int bidx = blk / 98;              // 98 blocks per batch (3136/32)
    const int bh_base = bidx * 12;
    const int tid = threadIdx.x;
    const int w = tid >> 6, l = tid & 63;
    const int l15 = l & 15, lq = l >> 4;

// issue all independent loads for head hh into named buffers
#define LOADH(aq, b0, b1, kse, kse1, hh) do {                                   \
    const int bh_ = bh_base + (hh);                                             \
    const __hip_bfloat16* kvh_ = kvb + ((size_t)bh_ << 12);                     \
    _Pragma("unroll")                                                           \
    for (int j = 0; j < 4; ++j) {                                               \
        b0[j] = *(const bf16x8*)(kvh_ + (j * 16 + l15) * 64 + lq * 8);          \
        b1[j] = *(const bf16x8*)(kvh_ + (j * 16 + l15) * 64 + 32 + lq * 8);     \
    }                                                                           \
    const __hip_bfloat16* q0_ = qkv + (m0 + l15) * 2304 + (hh) * 64;            \
    const __hip_bfloat16* q1_ = qkv + (m0 + 16 + l15) * 2304 + (hh) * 64;       \
    aq[0][0] = *(const bf16x8*)(q0_ + lq * 8);                                  \
    aq[0][1] = *(const bf16x8*)(q0_ + 32 + lq * 8);                             \
    aq[1][0] = *(const bf16x8*)(q1_ + lq * 8);                                  \
    aq[1][1] = *(const bf16x8*)(q1_ + 32 + lq * 8);                             \
    const float* ks_ = ksumg + (bh_ << 6);                                      \
    *(float4*)(kse)      = *(const float4*)(ks_ + lq * 8);                      \
    *(float4*)(kse + 4)  = *(const float4*)(ks_ + lq * 8 + 4);                  \
    *(float4*)(kse1)     = *(const float4*)(ks_ + 32 + lq * 8);                 \
    *(float4*)(kse1 + 4) = *(const float4*)(ks_ + 32 + lq * 8 + 4);             \
} while (0)

// attention compute for head hh from named buffers -> att_s columns
#define COMPH(aq, b0, b1, kse, kse1, hh) do {                                   \
    _Pragma("unroll")                                                           \
    for (int rt = 0; rt < 2; ++rt) {                                            \
        float zp = 0.0f;                                                        \
        _Pragma("unroll")                                                       \
        for (int j = 0; j < 8; ++j)                                             \
            zp += b2f(aq[rt][0][j]) * kse[j] + b2f(aq[rt][1][j]) * kse1[j];     \
        zp += __shfl_xor(zp, 16);                                               \
        zp += __shfl_xor(zp, 32);                                               \
        const float zr_ = 1.0f / (zp + EPS_Z);                                  \
        f32x4 pacc[4] = {};                                                     \
        _Pragma("unroll")                                                       \
        for (int j = 0; j < 4; ++j) {                                           \
            pacc[j] = __builtin_amdgcn_mfma_f32_16x16x32_bf16(aq[rt][0], b0[j], pacc[j], 0, 0, 0); \
            pacc[j] = __builtin_amdgcn_mfma_f32_16x16x32_bf16(aq[rt][1], b1[j], pacc[j], 0, 0, 0); \
        }                                                                       \
        float zrow[4];                                                          \
        _Pragma("unroll")                                                       \
        for (int r = 0; r < 4; ++r) zrow[r] = __shfl(zr_, lq * 4 + r);          \
        _Pragma("unroll")                                                       \
        for (int j = 0; j < 4; ++j)                                             \
            _Pragma("unroll")                                                   \
            for (int r = 0; r < 4; ++r)                                         \
                att_s[(rt * 16 + lq * 4 + r) * AS + (hh) * 64 + j * 16 + l15] = \
                    __float2bfloat16(pacc[j][r] * zrow[r]);                     \
    }                                                                           \
} while (0)

    // ---------------- phase A: 3 heads per wave, depth-1 pipeline ----------
    {
        bf16x8 aqA[2][2], aqB[2][2];
        bf16x8 bA0[4], bA1[4], bB0[4], bB1[4];
        float kseA[8], kse1A[8], kseB[8], kse1B[8];
        const int h0 = w * 3;
        LOADH(aqA, bA0, bA1, kseA, kse1A, h0);
        LOADH(aqB, bB0, bB1, kseB, kse1B, h0 + 1);
        COMPH(aqA, bA0, bA1, kseA, kse1A, h0);
        LOADH(aqA, bA0, bA1, kseA, kse1A, h0 + 2);
        COMPH(aqB, bB0, bB1, kseB, kse1B, h0 + 1);
        COMPH(aqA, bA0, bA1, kseA, kse1A, h0 + 2);
    }
    __syncthreads();

    // ---------------- phase B: out = att_s @ Wp^T + bias -------------------
#define LOADF(a0x, a1x, bx, kk) do {                                            \
    a0x = *(const bf16x8*)(att_s + l15 * AS + (kk) + lq * 8);                   \
    a1x = *(const bf16x8*)(att_s + (16 + l15) * AS + (kk) + lq * 8);            \
    _Pragma("unroll")                                                           \
    for (int j = 0; j < 6; ++j)                                                 \
        bx[j] = *(const bf16x8*)(wpb + (size_t)(c0 + j * 16 + l15) * 768 + (kk) + lq * 8); \
} while (0)

#define MFM(a0x, a1x, bx) do {                                                  \
    _Pragma("unroll")                                                           \
    for (int j = 0; j < 6; ++j) {                                               \
        acc[0][j] = __builtin_amdgcn_mfma_f32_16x16x32_bf16(a0x, bx[j], acc[0][j], 0, 0, 0); \
        acc[1][j] = __builtin_amdgcn_mfma_f32_16x16x32_bf16(a1x, bx[j], acc[1][j], 0, 0, 0); \
    }                                                                           \
} while (0)

    #pragma unroll 1
    for (int pass = 0; pass < 2; ++pass) {
        const int c0 = w * 192 + pass * 96;   // this wave's 96 output cols
        f32x4 acc[2][6] = {};
        bf16x8 aE0, aE1, bE[6], aO0, aO1, bO[6];
        LOADF(aE0, aE1, bE, 0);
        #pragma unroll 1
        for (int k0 = 0; k0 < 768; k0 += 64) {
            LOADF(aO0, aO1, bO, k0 + 32);
            MFM(aE0, aE1, bE);
            if (k0 + 64 < 768) LOADF(aE0, aE1, bE, k0 + 64);
            MFM(aO0, aO1, bO);
        }
        #pragma unroll
        for (int j = 0; j < 6; ++j) {
            const int gc = c0 + j * 16 + l15;
            const float badd = bias[gc];
            #pragma unroll
            for (int rt2 = 0; rt2 < 2; ++rt2) {
                #pragma unroll
                for (int r = 0; r < 4; ++r) {
                    const size_t gr = m0 + rt2 * 16 + lq * 4 + r;
                    out[gr * 768 + gc] = acc[rt2][j][r] + badd;
                }
            }
        }
    }
#undef LOADH
#undef COMPH
#undef LOADF
#undef MFM
}

extern "C" void kernel_launch(void* const* d_in, const int* in_sizes, int n_in,
                              void* d_out, int out_size, void* d_ws, size_t ws_size,
                              hipStream_t stream)
{
    const float* x      = (const float*)d_in[0];   // [25088, 768]
    const float* W_qkv  = (const float*)d_in[1];   // [2304, 768]
    const float* W_proj = (const float*)d_in[2];   // [768, 768]
    const float* b_proj = (const float*)d_in[3];   // [768]
    float* out = (float*)d_out;

    const int M = 25088, K = 768, N1 = 2304;
    const int SPLIT = 7;

    __hip_bfloat16* qkv = (__hip_bfloat16*)d_ws;            // M*N1
    __hip_bfloat16* xb  = qkv + (size_t)M * N1;             // M*K
    __hip_bfloat16* wqb = xb + (size_t)M * K;               // N1*K
    __hip_bfloat16* wpb = wqb + (size_t)N1 * K;             // 768*K
    float* kvp   = (float*)(wpb + (size_t)768 * K);         // 7*96*4096 fp32 partials
    float* ksump = kvp + (size_t)SPLIT * 96 * 4096;         // 7*96*64 fp32 partials
    float* ksum  = ksump + (size_t)SPLIT * 96 * 64;         // 96*64 fp32
    __hip_bfloat16* kvb = (__hip_bfloat16*)(ksum + 96 * 64);// 96*4096 bf16

    const int CVT_TOT = (M * K + N1 * K + 768 * K) / 4;
    cvt_all<<<(CVT_TOT + 255) / 256, 256, 0, stream>>>(x, W_qkv, W_proj, xb, wqb, wpb);

    gemm_bt<1, __hip_bfloat16><<<(M / 128) * (N1 / 128), 256, 0, stream>>>(
        xb, wqb, qkv, nullptr, K, N1, N1 / 128);

    kv_mfma_kernel<<<96 * SPLIT, 256, 0, stream>>>(qkv, kvp, ksump);
    kv_reduce<<<96, 256, 0, stream>>>(kvp, ksump, kvb, ksum);
    attn_proj<<<M / 32, 256, 0, stream>>>(qkv, kvb, ksum, wpb, b_proj, out);
}

// Round 7
// 330.005 us; speedup vs baseline: 1.3894x; 1.3173x over previous
//
#include <hip/hip_runtime.h>
#include <hip/hip_bf16.h>

#define EPS_Z 1e-4f

typedef __attribute__((ext_vector_type(8))) short bf16x8;
typedef __attribute__((ext_vector_type(4))) float f32x4;

__device__ __forceinline__ float b2f(short s) {
    union { unsigned u; float f; } cv;
    cv.u = ((unsigned)(unsigned short)s) << 16;
    return cv.f;
}

__device__ __forceinline__ void gld_lds16(const __hip_bfloat16* g, __hip_bfloat16* l) {
    __builtin_amdgcn_global_load_lds(
        (__attribute__((address_space(1))) void*)(g),
        (__attribute__((address_space(3))) void*)(l),
        16, 0, 0);
}

// One dispatch converting x, W_qkv, W_proj (fp32 -> bf16 RNE, 4 elems/thread).
__global__ __launch_bounds__(256)
void cvt_all(const float* __restrict__ x, const float* __restrict__ wq,
             const float* __restrict__ wp,
             __hip_bfloat16* __restrict__ xb, __hip_bfloat16* __restrict__ wqb,
             __hip_bfloat16* __restrict__ wpb)
{
    const int N4X = 25088 * 768 / 4;          // 4,816,896
    const int N4Q = 2304 * 768 / 4;           //   442,368
    const int N4P = 768 * 768 / 4;            //   147,456
    int i = blockIdx.x * 256 + threadIdx.x;
    const float* src;
    __hip_bfloat16* dst;
    int idx;
    if (i < N4X)            { src = x;  dst = xb;  idx = i; }
    else if (i < N4X + N4Q) { src = wq; dst = wqb; idx = i - N4X; }
    else if (i < N4X + N4Q + N4P) { src = wp; dst = wpb; idx = i - N4X - N4Q; }
    else return;
    float4 v = ((const float4*)src)[idx];
    union { short4 s; __hip_bfloat16 h[4]; } o;
    o.h[0] = __float2bfloat16(v.x);
    o.h[1] = __float2bfloat16(v.y);
    o.h[2] = __float2bfloat16(v.z);
    o.h[3] = __float2bfloat16(v.w);
    ((short4*)dst)[idx] = o.s;
}

// C[M,N] = A[M,K] @ B[N,K]^T ; A,B bf16, fp32 accumulate. 128x128 tile.
// PROVEN ~95 us (929 TF) on the QKV shape (R0/R2/R3). DO NOT TOUCH.
// m204 bijective XCD swizzle == R3's mapping for grid%8==0 (3528, 1176 both are).
// MODE 1: relu on cols < 1536, C bf16. MODE 2: += fp32 bias, C fp32.
template<int MODE, typename CT>
__global__ __launch_bounds__(256, 3)
void gemm_bt(const __hip_bfloat16* __restrict__ A,
             const __hip_bfloat16* __restrict__ B,
             CT* __restrict__ C,
             const float* __restrict__ bias,
             int K, int N, int gx)
{
    __shared__ __align__(16) __hip_bfloat16 As[128 * 64];
    __shared__ __align__(16) __hip_bfloat16 Bs[128 * 64];
    const int nwg = (int)gridDim.x;
    const int g = blockIdx.x;
    const int xcd = g & 7, lin = g >> 3;
    const int q = nwg >> 3, r = nwg & 7;
    const int gp = (xcd < r ? xcd * (q + 1) : r * (q + 1) + (xcd - r) * q) + lin;
    const int bx = gp % gx;
    const int by = gp / gx;

    const int tid = threadIdx.x;
    const int w = tid >> 6;
    const int l = tid & 63;
    const int wr = (w >> 1) * 64;
    const int wc = (w & 1) * 64;
    const int l15 = l & 15;
    const int lq = l >> 4;
    const int rx = l15 & 7;

    f32x4 acc[4][4] = {};

    const int srow8 = l >> 3;
    const int scol = (((l & 7) ^ (l >> 3)) << 3);

    const __hip_bfloat16* Ab = A + (size_t)by * 128 * K;
    const __hip_bfloat16* Bb = B + (size_t)bx * 128 * K;

    for (int k0 = 0; k0 < K; k0 += 64) {
        __syncthreads();
        #pragma unroll
        for (int i = 0; i < 4; ++i) {
            const int chunk = w * 4 + i;
            const int row = chunk * 8 + srow8;
            gld_lds16(Ab + (size_t)row * K + (k0 + scol), As + chunk * 512);
            gld_lds16(Bb + (size_t)row * K + (k0 + scol), Bs + chunk * 512);
        }
        __syncthreads();
        #pragma unroll
        for (int kk = 0; kk < 64; kk += 32) {
            const int kb = (kk >> 3) + lq;
            const int col = (kb ^ rx) << 3;
            bf16x8 a[4], b[4];
            #pragma unroll
            for (int i = 0; i < 4; ++i)
                a[i] = *(const bf16x8*)(As + (wr + i * 16 + l15) * 64 + col);
            #pragma unroll
            for (int j = 0; j < 4; ++j)
                b[j] = *(const bf16x8*)(Bs + (wc + j * 16 + l15) * 64 + col);
            #pragma unroll
            for (int i = 0; i < 4; ++i)
                #pragma unroll
                for (int j = 0; j < 4; ++j)
                    acc[i][j] = __builtin_amdgcn_mfma_f32_16x16x32_bf16(a[i], b[j], acc[i][j], 0, 0, 0);
        }
    }

    const int crow0 = by * 128 + wr + lq * 4;
    const int ccol0 = bx * 128 + wc + l15;
    #pragma unroll
    for (int i = 0; i < 4; ++i) {
        #pragma unroll
        for (int j = 0; j < 4; ++j) {
            const int gc = ccol0 + j * 16;
            const float badd = (MODE == 2) ? bias[gc] : 0.0f;
            #pragma unroll
            for (int r2 = 0; r2 < 4; ++r2) {
                const int gr = crow0 + i * 16 + r2;
                float v = acc[i][j][r2];
                if (MODE == 1 && gc < 1536) v = fmaxf(v, 0.0f);
                if (MODE == 2) v += badd;
                if (MODE == 1)
                    ((__hip_bfloat16*)C)[(size_t)gr * N + gc] = __float2bfloat16(v);
                else
                    ((float*)C)[(size_t)gr * N + gc] = v;
            }
        }
    }
}

// kv^T partials: kvp[(bh*7+ck)][d][e] = sum_{s in split ck} v[s,d]*k[s,e]
// ksump[(bh*7+ck)][e] = sum_{s in split ck} k[s,e]  (all-ones A-fragment MFMA)
// Software-pipelined prefetch of next s-block's global loads under MFMA. (R3)
__global__ __launch_bounds__(256)
void kv_mfma_kernel(const __hip_bfloat16* __restrict__ qkv,
                    float* __restrict__ kvp, float* __restrict__ ksump)
{
    const int SPLIT = 7;
    const int bh = blockIdx.x / SPLIT;
    const int ck = blockIdx.x % SPLIT;
    const int b = bh / 12, h = bh % 12;

    __shared__ __align__(16) __hip_bfloat16 kT[64 * 40];   // [e][s0..31], stride 40
    __shared__ __align__(16) __hip_bfloat16 vT[64 * 40];   // [d][s0..31]

    const int tid = threadIdx.x;
    const int w = tid >> 6, l = tid & 63;
    const int l15 = l & 15, lq = l >> 4;

    const int half = tid >> 7;        // 0 -> stage k, 1 -> stage v
    const int idx  = tid & 127;
    const int e0 = (idx >> 4) * 8;
    const int sp = idx & 15;

    const size_t rowbase = (size_t)b * 3136 * 2304 + (half ? 1536 : 768) + h * 64 + e0;
    __hip_bfloat16* Tdst = half ? vT : kT;

    f32x4 acc[4] = {};
    f32x4 accks = {};

    bf16x8 ones;
    #pragma unroll
    for (int i = 0; i < 8; ++i) ones[i] = (short)0x3F80;   // bf16 1.0

    const int s_begin = ck * 448;
    const int s_end = s_begin + 448;

    bf16x8 r0 = *(const bf16x8*)(qkv + rowbase + (size_t)(s_begin + 2 * sp) * 2304);
    bf16x8 r1 = *(const bf16x8*)(qkv + rowbase + (size_t)(s_begin + 2 * sp + 1) * 2304);

    for (int s0 = s_begin; s0 < s_end; s0 += 32) {
        __syncthreads();   // previous compute done reading LDS
        #pragma unroll
        for (int qq = 0; qq < 8; ++qq) {
            unsigned pk = ((unsigned)(unsigned short)r0[qq]) |
                          (((unsigned)(unsigned short)r1[qq]) << 16);
            *(unsigned*)(Tdst + (e0 + qq) * 40 + 2 * sp) = pk;
        }
        __syncthreads();   // staged data visible
        if (s0 + 32 < s_end) {   // prefetch next block; hides under MFMA below
            r0 = *(const bf16x8*)(qkv + rowbase + (size_t)(s0 + 32 + 2 * sp) * 2304);
            r1 = *(const bf16x8*)(qkv + rowbase + (size_t)(s0 + 33 + 2 * sp) * 2304);
        }
        bf16x8 a = *(const bf16x8*)(vT + (w * 16 + l15) * 40 + lq * 8);
        bf16x8 bfr[4];
        #pragma unroll
        for (int j = 0; j < 4; ++j)
            bfr[j] = *(const bf16x8*)(kT + (j * 16 + l15) * 40 + lq * 8);
        #pragma unroll
        for (int j = 0; j < 4; ++j)
            acc[j] = __builtin_amdgcn_mfma_f32_16x16x32_bf16(a, bfr[j], acc[j], 0, 0, 0);
        accks = __builtin_amdgcn_mfma_f32_16x16x32_bf16(ones, bfr[w], accks, 0, 0, 0);
    }

    float* kvdst = kvp + ((size_t)(bh * SPLIT + ck) << 12);
    #pragma unroll
    for (int j = 0; j < 4; ++j) {
        const int col = j * 16 + l15;
        #pragma unroll
        for (int r = 0; r < 4; ++r) {
            const int row = w * 16 + lq * 4 + r;
            kvdst[row * 64 + col] = acc[j][r];
        }
    }
    if (lq == 0)
        ksump[(size_t)(bh * SPLIT + ck) * 64 + w * 16 + l15] = accks[0];
}

// Sum the 7 fp32 partials -> kvb (bf16) and ksum (fp32). (R3)
__global__ __launch_bounds__(256)
void kv_reduce(const float* __restrict__ kvp, const float* __restrict__ ksump,
               __hip_bfloat16* __restrict__ kvb, float* __restrict__ ksum)
{
    const int SPLIT = 7;
    const int bh = blockIdx.x;
    const int tid = threadIdx.x;

    const float* base = kvp + ((size_t)bh * SPLIT << 12) + tid * 16;
    float4 s0 = {}, s1 = {}, s2 = {}, s3 = {};
    #pragma unroll
    for (int p = 0; p < SPLIT; ++p) {
        const float* bp = base + ((size_t)p << 12);
        float4 a0 = *(const float4*)(bp + 0);
        float4 a1 = *(const float4*)(bp + 4);
        float4 a2 = *(const float4*)(bp + 8);
        float4 a3 = *(const float4*)(bp + 12);
        s0.x += a0.x; s0.y += a0.y; s0.z += a0.z; s0.w += a0.w;
        s1.x += a1.x; s1.y += a1.y; s1.z += a1.z; s1.w += a1.w;
        s2.x += a2.x; s2.y += a2.y; s2.z += a2.z; s2.w += a2.w;
        s3.x += a3.x; s3.y += a3.y; s3.z += a3.z; s3.w += a3.w;
    }
    union { bf16x8 v; __hip_bfloat16 h[8]; } o0, o1;
    o0.h[0] = __float2bfloat16(s0.x); o0.h[1] = __float2bfloat16(s0.y);
    o0.h[2] = __float2bfloat16(s0.z); o0.h[3] = __float2bfloat16(s0.w);
    o0.h[4] = __float2bfloat16(s1.x); o0.h[5] = __float2bfloat16(s1.y);
    o0.h[6] = __float2bfloat16(s1.z); o0.h[7] = __float2bfloat16(s1.w);
    o1.h[0] = __float2bfloat16(s2.x); o1.h[1] = __float2bfloat16(s2.y);
    o1.h[2] = __float2bfloat16(s2.z); o1.h[3] = __float2bfloat16(s2.w);
    o1.h[4] = __float2bfloat16(s3.x); o1.h[5] = __float2bfloat16(s3.y);
    o1.h[6] = __float2bfloat16(s3.z); o1.h[7] = __float2bfloat16(s3.w);
    __hip_bfloat16* dst = kvb + ((size_t)bh << 12) + tid * 16;
    *(bf16x8*)(dst + 0) = o0.v;
    *(bf16x8*)(dst + 8) = o1.v;

    if (tid < 64) {
        float t = 0.0f;
        #pragma unroll
        for (int p = 0; p < SPLIT; ++p)
            t += ksump[(size_t)(bh * SPLIT + p) * 64 + tid];
        ksum[(size_t)bh * 64 + tid] = t;
    }
}

// att[m, h*64+d] = (q[m,:] @ kv^T[d,:]) * 1/(q[m,:].ksum + eps)
// 2 row-tiles (2x64 rows) per block: kvb B-fragments + ksum loaded once, reused. (R3)
__global__ __launch_bounds__(256)
void attn_mfma2(const __hip_bfloat16* __restrict__ qkv,
                const __hip_bfloat16* __restrict__ kvb,
                const float* __restrict__ ksumg,
                __hip_bfloat16* __restrict__ att)
{
    const int bh = blockIdx.x / 25;
    const int u  = blockIdx.x % 25;
    const int b = bh / 12, h = bh % 12;
    const int tid = threadIdx.x;
    const int w = tid >> 6, l = tid & 63;
    const int l15 = l & 15, lq = l >> 4;

    // B-fragments from kvb[bh][d][e] (row-major, stride 64) -- loaded once
    const __hip_bfloat16* kvh = kvb + ((size_t)bh << 12);
    bf16x8 b0[4], b1[4];
    #pragma unroll
    for (int j = 0; j < 4; ++j) {
        b0[j] = *(const bf16x8*)(kvh + (j * 16 + l15) * 64 + lq * 8);
        b1[j] = *(const bf16x8*)(kvh + (j * 16 + l15) * 64 + 32 + lq * 8);
    }
    const float* ks = ksumg + (bh << 6);
    float kse[8], kse1[8];
    *(float4*)(kse)      = *(const float4*)(ks + lq * 8);
    *(float4*)(kse + 4)  = *(const float4*)(ks + lq * 8 + 4);
    *(float4*)(kse1)     = *(const float4*)(ks + 32 + lq * 8);
    *(float4*)(kse1 + 4) = *(const float4*)(ks + 32 + lq * 8 + 4);

    #pragma unroll
    for (int t = 0; t < 2; ++t) {
        const int mt = u * 2 + t;
        if (mt >= 49) break;
        const size_t m0 = (size_t)b * 3136 + (size_t)mt * 64 + w * 16;

        const __hip_bfloat16* qrow = qkv + (m0 + l15) * 2304 + h * 64;
        bf16x8 aq0 = *(const bf16x8*)(qrow + lq * 8);
        bf16x8 aq1 = *(const bf16x8*)(qrow + 32 + lq * 8);

        float zp = 0.0f;
        #pragma unroll
        for (int j = 0; j < 8; ++j)
            zp += b2f(aq0[j]) * kse[j] + b2f(aq1[j]) * kse1[j];
        zp += __shfl_xor(zp, 16);
        zp += __shfl_xor(zp, 32);
        const float zr = 1.0f / (zp + EPS_Z);   // lane i<16 holds z-recip for row i

        f32x4 acc[4] = {};
        #pragma unroll
        for (int j = 0; j < 4; ++j) {
            acc[j] = __builtin_amdgcn_mfma_f32_16x16x32_bf16(aq0, b0[j], acc[j], 0, 0, 0);
            acc[j] = __builtin_amdgcn_mfma_f32_16x16x32_bf16(aq1, b1[j], acc[j], 0, 0, 0);
        }

        float zrow[4];
        #pragma unroll
        for (int r = 0; r < 4; ++r) zrow[r] = __shfl(zr, lq * 4 + r);

        #pragma unroll
        for (int j = 0; j < 4; ++j) {
            const int col = j * 16 + l15;
            #pragma unroll
            for (int r = 0; r < 4; ++r) {
                const int row = lq * 4 + r;
                att[(m0 + row) * 768 + h * 64 + col] = __float2bfloat16(acc[j][r] * zrow[r]);
            }
        }
    }
}

extern "C" void kernel_launch(void* const* d_in, const int* in_sizes, int n_in,
                              void* d_out, int out_size, void* d_ws, size_t ws_size,
                              hipStream_t stream)
{
    const float* x      = (const float*)d_in[0];   // [25088, 768]
    const float* W_qkv  = (const float*)d_in[1];   // [2304, 768]
    const float* W_proj = (const float*)d_in[2];   // [768, 768]
    const float* b_proj = (const float*)d_in[3];   // [768]
    float* out = (float*)d_out;

    const int M = 25088, K = 768, N1 = 2304, N2 = 768;
    const int SPLIT = 7;

    __hip_bfloat16* qkv = (__hip_bfloat16*)d_ws;            // M*N1
    __hip_bfloat16* xb  = qkv + (size_t)M * N1;             // M*K
    __hip_bfloat16* wqb = xb + (size_t)M * K;               // N1*K
    __hip_bfloat16* wpb = wqb + (size_t)N1 * K;             // N2*K
    float* kvp   = (float*)(wpb + (size_t)N2 * K);          // 7*96*4096 fp32 partials
    float* ksump = kvp + (size_t)SPLIT * 96 * 4096;         // 7*96*64 fp32 partials
    float* ksum  = ksump + (size_t)SPLIT * 96 * 64;         // 96*64 fp32
    __hip_bfloat16* kvb = (__hip_bfloat16*)(ksum + 96 * 64);// 96*4096 bf16
    __hip_bfloat16* att = xb;                               // alias: M*N2 <= M*K

    const int CVT_TOT = (M * K + N1 * K + N2 * K) / 4;
    cvt_all<<<(CVT_TOT + 255) / 256, 256, 0, stream>>>(x, W_qkv, W_proj, xb, wqb, wpb);

    gemm_bt<1, __hip_bfloat16><<<(M / 128) * (N1 / 128), 256, 0, stream>>>(
        xb, wqb, qkv, nullptr, K, N1, N1 / 128);
    kv_mfma_kernel<<<96 * SPLIT, 256, 0, stream>>>(qkv, kvp, ksump);
    kv_reduce<<<96, 256, 0, stream>>>(kvp, ksump, kvb, ksum);
    attn_mfma2<<<96 * 25, 256, 0, stream>>>(qkv, kvb, ksum, att);
    gemm_bt<2, float><<<(M / 128) * (N2 / 128), 256, 0, stream>>>(
        att, wpb, out, b_proj, K, N2, N2 / 128);
}